// Round 1
// baseline (214.366 us; speedup 1.0000x reference)
//
#include <hip/hip_runtime.h>

#define BB   4
#define QS   512
#define KSZ  1024
#define DD   512
#define HH   128
#define DVV  512

__device__ __forceinline__ float rcp_fast(float x)  { return __builtin_amdgcn_rcpf(x); }
__device__ __forceinline__ float exp2_fast(float x) { return __builtin_amdgcn_exp2f(x); }

// ---------------------------------------------------------------------------
// Kernel A: fused projection + exp(2x).
// out[m][h] = exp2( 2*log2(e) * dot(A[m,:], W[:,h]) )
// Handles BOTH q-projection and k-projection in one launch: blocks
// [0, nq_blocks) do queries@W_q -> eq, the rest do keys@W_k -> ek.
// 16 rows per block, 256 threads.
// ---------------------------------------------------------------------------
__global__ __launch_bounds__(256) void proj_exp_kernel(
    const float* __restrict__ q,  const float* __restrict__ k,
    const float* __restrict__ Wq, const float* __restrict__ Wk,
    float* __restrict__ eq, float* __restrict__ ek, int nq_blocks)
{
    __shared__ float At[16][36];    // +4 pad: row stride 36 floats (16B aligned)
    __shared__ float Wt[32][128];

    const float* A; const float* W; float* outp; int m0;
    if ((int)blockIdx.x < nq_blocks) {
        A = q;  W = Wq; outp = eq; m0 = blockIdx.x * 16;
    } else {
        A = k;  W = Wk; outp = ek; m0 = (blockIdx.x - nq_blocks) * 16;
    }

    const int tid = threadIdx.x;
    const int h4  = tid & 31;   // h columns [h4*4, h4*4+4)
    const int r   = tid >> 5;   // rows r and r+8

    float4 acc0 = {0.f,0.f,0.f,0.f};
    float4 acc1 = {0.f,0.f,0.f,0.f};

    for (int d0 = 0; d0 < DD; d0 += 32) {
        if (tid < 128) {                       // 16x32 A tile = 128 float4
            int row = tid >> 3, c4 = tid & 7;
            *(float4*)&At[row][c4 * 4] =
                *(const float4*)&A[(size_t)(m0 + row) * DD + d0 + c4 * 4];
        }
        #pragma unroll
        for (int i = 0; i < 4; i++) {          // 32x128 W tile = 1024 float4
            int f = tid + i * 256;
            int row = f >> 5, c4 = f & 31;
            *(float4*)&Wt[row][c4 * 4] =
                *(const float4*)&W[(size_t)(d0 + row) * HH + c4 * 4];
        }
        __syncthreads();
        #pragma unroll 4
        for (int kk = 0; kk < 32; kk++) {
            float4 w4 = *(const float4*)&Wt[kk][h4 * 4];
            float a0 = At[r][kk];
            float a1 = At[r + 8][kk];
            acc0.x = fmaf(a0, w4.x, acc0.x); acc0.y = fmaf(a0, w4.y, acc0.y);
            acc0.z = fmaf(a0, w4.z, acc0.z); acc0.w = fmaf(a0, w4.w, acc0.w);
            acc1.x = fmaf(a1, w4.x, acc1.x); acc1.y = fmaf(a1, w4.y, acc1.y);
            acc1.z = fmaf(a1, w4.z, acc1.z); acc1.w = fmaf(a1, w4.w, acc1.w);
        }
        __syncthreads();
    }

    const float C2L = 2.8853900817779268f;  // 2*log2(e):  exp(2x)=2^(x*C2L)
    float4 o0, o1;
    o0.x = exp2_fast(acc0.x * C2L); o0.y = exp2_fast(acc0.y * C2L);
    o0.z = exp2_fast(acc0.z * C2L); o0.w = exp2_fast(acc0.w * C2L);
    o1.x = exp2_fast(acc1.x * C2L); o1.y = exp2_fast(acc1.y * C2L);
    o1.z = exp2_fast(acc1.z * C2L); o1.w = exp2_fast(acc1.w * C2L);
    *(float4*)&outp[(size_t)(m0 + r)     * HH + h4 * 4] = o0;
    *(float4*)&outp[(size_t)(m0 + r + 8) * HH + h4 * 4] = o1;
}

// ---------------------------------------------------------------------------
// Kernel B: scores[b][q][k] = -2 * sum_h w_v[h] * rcp(eq[b,q,h]*ek[b,k,h] + 1)
// (constant sum(w_v) dropped -- cancels in softmax; tanh(q+k) factored via
//  exp(2q)*exp(2k)). 64x64 tile per WG, thread tile 4q x 4k (stride-16).
// LDS padded to stride 68 -> conflict-free fragment reads.
// ---------------------------------------------------------------------------
__global__ __launch_bounds__(256) void scores_kernel(
    const float* __restrict__ eq, const float* __restrict__ ek,
    const float* __restrict__ wv, float* __restrict__ sc)
{
    __shared__ float eqs[64][68];
    __shared__ float eks[64][68];
    __shared__ float wvs[HH];

    const int tid = threadIdx.x;
    const int b  = blockIdx.z;
    const int q0 = blockIdx.y * 64;
    const int k0 = blockIdx.x * 64;

    const float* eqb = eq + ((size_t)b * QS  + q0) * HH;
    const float* ekb = ek + ((size_t)b * KSZ + k0) * HH;

    if (tid < 32) *(float4*)&wvs[tid * 4] = *(const float4*)&wv[tid * 4];

    const int tk = tid & 15;   // k cols: k0 + tk + 16*jk
    const int tq = tid >> 4;   // q rows: q0 + tq + 16*jq

    float acc[4][4] = {};

    for (int hc = 0; hc < HH; hc += 64) {
        __syncthreads();
        #pragma unroll
        for (int i = 0; i < 4; i++) {          // 64 rows x 64 floats = 1024 f4
            int f = tid + i * 256;
            int row = f >> 4, c4 = f & 15;
            *(float4*)&eqs[row][c4 * 4] =
                *(const float4*)&eqb[(size_t)row * HH + hc + c4 * 4];
            *(float4*)&eks[row][c4 * 4] =
                *(const float4*)&ekb[(size_t)row * HH + hc + c4 * 4];
        }
        __syncthreads();

        for (int h0 = 0; h0 < 64; h0 += 4) {
            float4 wv4 = *(const float4*)&wvs[hc + h0];
            float4 eq4[4], ek4[4];
            #pragma unroll
            for (int j = 0; j < 4; j++) {
                eq4[j] = *(const float4*)&eqs[tq + 16 * j][h0];
                ek4[j] = *(const float4*)&eks[tk + 16 * j][h0];
            }
            #pragma unroll
            for (int jq = 0; jq < 4; jq++) {
                #pragma unroll
                for (int jk = 0; jk < 4; jk++) {
                    acc[jq][jk] = fmaf(wv4.x, rcp_fast(fmaf(eq4[jq].x, ek4[jk].x, 1.0f)), acc[jq][jk]);
                    acc[jq][jk] = fmaf(wv4.y, rcp_fast(fmaf(eq4[jq].y, ek4[jk].y, 1.0f)), acc[jq][jk]);
                    acc[jq][jk] = fmaf(wv4.z, rcp_fast(fmaf(eq4[jq].z, ek4[jk].z, 1.0f)), acc[jq][jk]);
                    acc[jq][jk] = fmaf(wv4.w, rcp_fast(fmaf(eq4[jq].w, ek4[jk].w, 1.0f)), acc[jq][jk]);
                }
            }
        }
    }

    float* scb = sc + ((size_t)b * QS + q0) * KSZ + k0;
    #pragma unroll
    for (int jq = 0; jq < 4; jq++)
        #pragma unroll
        for (int jk = 0; jk < 4; jk++)
            scb[(size_t)(tq + 16 * jq) * KSZ + tk + 16 * jk] = -2.0f * acc[jq][jk];
}

// ---------------------------------------------------------------------------
// Kernel C: per (b, 8 q-rows, 256 v-cols): softmax over K=1024, then P @ V.
// Raw exp() kept in LDS; normalization folded into epilogue (rcp(rowsum)).
// ---------------------------------------------------------------------------
__global__ __launch_bounds__(256) void softmax_av_kernel(
    const float* __restrict__ sc, const float* __restrict__ val,
    float* __restrict__ outp)
{
    __shared__ float p[8][1028];     // +4 pad, 16B-aligned rows
    __shared__ float vs[8][256];
    __shared__ float rowsum[8];

    const int tid   = threadIdx.x;
    const int vbase = blockIdx.x * 256;
    const int q0    = blockIdx.y * 8;
    const int b     = blockIdx.z;

    const float* scb = sc + ((size_t)b * QS + q0) * KSZ;

    // load 8x1024 scores
    #pragma unroll
    for (int i = 0; i < 8; i++) {
        int f = tid + i * 256;       // 2048 float4
        int row = f >> 8, c4 = f & 255;
        *(float4*)&p[row][c4 * 4] = *(const float4*)&scb[(size_t)row * KSZ + c4 * 4];
    }
    __syncthreads();

    // softmax (raw exp + rowsum); 32 lanes per row
    {
        const int row = tid >> 5, l = tid & 31;
        float m = -1e30f;
        #pragma unroll 8
        for (int i = 0; i < 32; i++) m = fmaxf(m, p[row][l + 32 * i]);
        #pragma unroll
        for (int mask = 16; mask; mask >>= 1) m = fmaxf(m, __shfl_xor(m, mask, 32));
        float s = 0.f;
        #pragma unroll 8
        for (int i = 0; i < 32; i++) {
            float e = exp2_fast((p[row][l + 32 * i] - m) * 1.44269504f);
            p[row][l + 32 * i] = e;
            s += e;
        }
        #pragma unroll
        for (int mask = 16; mask; mask >>= 1) s += __shfl_xor(s, mask, 32);
        if (l == 0) rowsum[row] = s;
    }

    const int tv = tid & 63;   // v cols: vbase + tv*4 .. +4
    const int tq = tid >> 6;   // q rows: tq and tq+4
    float4 acc[2] = {{0.f,0.f,0.f,0.f},{0.f,0.f,0.f,0.f}};
    const float* vb = val + (size_t)b * KSZ * DVV + vbase;

    for (int k0 = 0; k0 < KSZ; k0 += 8) {
        __syncthreads();                       // protect vs reuse (and first: p ready)
        #pragma unroll
        for (int i = 0; i < 2; i++) {          // 8x256 = 512 float4
            int f = tid + i * 256;
            int row = f >> 6, c4 = f & 63;
            *(float4*)&vs[row][c4 * 4] =
                *(const float4*)&vb[(size_t)(k0 + row) * DVV + c4 * 4];
        }
        __syncthreads();

        #pragma unroll
        for (int kk = 0; kk < 8; kk += 4) {
            float4 p4[2], v4[4];
            #pragma unroll
            for (int j = 0; j < 2; j++)
                p4[j] = *(const float4*)&p[tq + 4 * j][k0 + kk];
            #pragma unroll
            for (int c = 0; c < 4; c++)
                v4[c] = *(const float4*)&vs[kk + c][tv * 4];
            #pragma unroll
            for (int j = 0; j < 2; j++) {
                acc[j].x = fmaf(p4[j].x, v4[0].x, acc[j].x);
                acc[j].y = fmaf(p4[j].x, v4[0].y, acc[j].y);
                acc[j].z = fmaf(p4[j].x, v4[0].z, acc[j].z);
                acc[j].w = fmaf(p4[j].x, v4[0].w, acc[j].w);
                acc[j].x = fmaf(p4[j].y, v4[1].x, acc[j].x);
                acc[j].y = fmaf(p4[j].y, v4[1].y, acc[j].y);
                acc[j].z = fmaf(p4[j].y, v4[1].z, acc[j].z);
                acc[j].w = fmaf(p4[j].y, v4[1].w, acc[j].w);
                acc[j].x = fmaf(p4[j].z, v4[2].x, acc[j].x);
                acc[j].y = fmaf(p4[j].z, v4[2].y, acc[j].y);
                acc[j].z = fmaf(p4[j].z, v4[2].z, acc[j].z);
                acc[j].w = fmaf(p4[j].z, v4[2].w, acc[j].w);
                acc[j].x = fmaf(p4[j].w, v4[3].x, acc[j].x);
                acc[j].y = fmaf(p4[j].w, v4[3].y, acc[j].y);
                acc[j].z = fmaf(p4[j].w, v4[3].z, acc[j].z);
                acc[j].w = fmaf(p4[j].w, v4[3].w, acc[j].w);
            }
        }
    }

    float* ob = outp + ((size_t)b * QS + q0) * DVV + vbase;
    #pragma unroll
    for (int j = 0; j < 2; j++) {
        float inv = rcp_fast(rowsum[tq + 4 * j]);
        float4 o;
        o.x = acc[j].x * inv; o.y = acc[j].y * inv;
        o.z = acc[j].z * inv; o.w = acc[j].w * inv;
        *(float4*)&ob[(size_t)(tq + 4 * j) * DVV + tv * 4] = o;
    }
}

// ---------------------------------------------------------------------------
extern "C" void kernel_launch(void* const* d_in, const int* in_sizes, int n_in,
                              void* d_out, int out_size, void* d_ws, size_t ws_size,
                              hipStream_t stream)
{
    const float* queries = (const float*)d_in[0];
    const float* keys    = (const float*)d_in[1];
    const float* values  = (const float*)d_in[2];
    const float* Wq      = (const float*)d_in[3];
    const float* Wk      = (const float*)d_in[4];
    const float* wv      = (const float*)d_in[5];
    float* out = (float*)d_out;

    // workspace layout (floats): eq [B*Q*H] | ek [B*K*H] | scores [B*Q*K]
    float* eq = (float*)d_ws;
    float* ek = eq + (size_t)BB * QS * HH;      // + 262144
    float* sc = ek + (size_t)BB * KSZ * HH;     // + 524288  (scores: 2097152 floats)

    const int nq_blocks = BB * QS / 16;   // 128
    const int nk_blocks = BB * KSZ / 16;  // 256
    proj_exp_kernel<<<dim3(nq_blocks + nk_blocks), 256, 0, stream>>>(
        queries, keys, Wq, Wk, eq, ek, nq_blocks);

    scores_kernel<<<dim3(KSZ / 64, QS / 64, BB), 256, 0, stream>>>(eq, ek, wv, sc);

    softmax_av_kernel<<<dim3(DVV / 256, QS / 8, BB), 256, 0, stream>>>(sc, values, out);
}

// Round 2
// 171.784 us; speedup vs baseline: 1.2479x; 1.2479x over previous
//
#include <hip/hip_runtime.h>

#define BB   4
#define QS   512
#define KSZ  1024
#define DD   512
#define HH   128
#define DVV  512

__device__ __forceinline__ float rcp_fast(float x)  { return __builtin_amdgcn_rcpf(x); }
__device__ __forceinline__ float exp2_fast(float x) { return __builtin_amdgcn_exp2f(x); }

// ---------------------------------------------------------------------------
// Kernel A: fused projection + exp(2x).
// out[m][h] = exp2( 2*log2(e) * dot(A[m,:], W[:,h]) )
// Blocks [0, nq_blocks) do queries@W_q -> eq, the rest do keys@W_k -> ek.
// ---------------------------------------------------------------------------
__global__ __launch_bounds__(256) void proj_exp_kernel(
    const float* __restrict__ q,  const float* __restrict__ k,
    const float* __restrict__ Wq, const float* __restrict__ Wk,
    float* __restrict__ eq, float* __restrict__ ek, int nq_blocks)
{
    __shared__ float At[16][36];    // +4 pad
    __shared__ float Wt[32][128];

    const float* A; const float* W; float* outp; int m0;
    if ((int)blockIdx.x < nq_blocks) {
        A = q;  W = Wq; outp = eq; m0 = blockIdx.x * 16;
    } else {
        A = k;  W = Wk; outp = ek; m0 = (blockIdx.x - nq_blocks) * 16;
    }

    const int tid = threadIdx.x;
    const int h4  = tid & 31;
    const int r   = tid >> 5;

    float4 acc0 = {0.f,0.f,0.f,0.f};
    float4 acc1 = {0.f,0.f,0.f,0.f};

    for (int d0 = 0; d0 < DD; d0 += 32) {
        if (tid < 128) {
            int row = tid >> 3, c4 = tid & 7;
            *(float4*)&At[row][c4 * 4] =
                *(const float4*)&A[(size_t)(m0 + row) * DD + d0 + c4 * 4];
        }
        #pragma unroll
        for (int i = 0; i < 4; i++) {
            int f = tid + i * 256;
            int row = f >> 5, c4 = f & 31;
            *(float4*)&Wt[row][c4 * 4] =
                *(const float4*)&W[(size_t)(d0 + row) * HH + c4 * 4];
        }
        __syncthreads();
        #pragma unroll 4
        for (int kk = 0; kk < 32; kk++) {
            float4 w4 = *(const float4*)&Wt[kk][h4 * 4];
            float a0 = At[r][kk];
            float a1 = At[r + 8][kk];
            acc0.x = fmaf(a0, w4.x, acc0.x); acc0.y = fmaf(a0, w4.y, acc0.y);
            acc0.z = fmaf(a0, w4.z, acc0.z); acc0.w = fmaf(a0, w4.w, acc0.w);
            acc1.x = fmaf(a1, w4.x, acc1.x); acc1.y = fmaf(a1, w4.y, acc1.y);
            acc1.z = fmaf(a1, w4.z, acc1.z); acc1.w = fmaf(a1, w4.w, acc1.w);
        }
        __syncthreads();
    }

    const float C2L = 2.8853900817779268f;  // 2*log2(e)
    float4 o0, o1;
    o0.x = exp2_fast(acc0.x * C2L); o0.y = exp2_fast(acc0.y * C2L);
    o0.z = exp2_fast(acc0.z * C2L); o0.w = exp2_fast(acc0.w * C2L);
    o1.x = exp2_fast(acc1.x * C2L); o1.y = exp2_fast(acc1.y * C2L);
    o1.z = exp2_fast(acc1.z * C2L); o1.w = exp2_fast(acc1.w * C2L);
    *(float4*)&outp[(size_t)(m0 + r)     * HH + h4 * 4] = o0;
    *(float4*)&outp[(size_t)(m0 + r + 8) * HH + h4 * 4] = o1;
}

// ---------------------------------------------------------------------------
// Kernel B: sc[b][q][k] = sum_h w_v[h] * rcp(eq[b,q,h]*ek[b,k,h] + 1)
// True scores = -2*sc + const (const dropped -- cancels in softmax; the -2
// is folded into the exp2 constant of pv_gemm_kernel).
// ---------------------------------------------------------------------------
__global__ __launch_bounds__(256) void scores_kernel(
    const float* __restrict__ eq, const float* __restrict__ ek,
    const float* __restrict__ wv, float* __restrict__ sc)
{
    __shared__ float eqs[64][68];
    __shared__ float eks[64][68];
    __shared__ float wvs[HH];

    const int tid = threadIdx.x;
    const int b  = blockIdx.z;
    const int q0 = blockIdx.y * 64;
    const int k0 = blockIdx.x * 64;

    const float* eqb = eq + ((size_t)b * QS  + q0) * HH;
    const float* ekb = ek + ((size_t)b * KSZ + k0) * HH;

    if (tid < 32) *(float4*)&wvs[tid * 4] = *(const float4*)&wv[tid * 4];

    const int tk = tid & 15;
    const int tq = tid >> 4;

    float acc[4][4] = {};

    for (int hc = 0; hc < HH; hc += 64) {
        __syncthreads();
        #pragma unroll
        for (int i = 0; i < 4; i++) {
            int f = tid + i * 256;
            int row = f >> 4, c4 = f & 15;
            *(float4*)&eqs[row][c4 * 4] =
                *(const float4*)&eqb[(size_t)row * HH + hc + c4 * 4];
            *(float4*)&eks[row][c4 * 4] =
                *(const float4*)&ekb[(size_t)row * HH + hc + c4 * 4];
        }
        __syncthreads();

        for (int h0 = 0; h0 < 64; h0 += 4) {
            float4 wv4 = *(const float4*)&wvs[hc + h0];
            float4 eq4[4], ek4[4];
            #pragma unroll
            for (int j = 0; j < 4; j++) {
                eq4[j] = *(const float4*)&eqs[tq + 16 * j][h0];
                ek4[j] = *(const float4*)&eks[tk + 16 * j][h0];
            }
            #pragma unroll
            for (int jq = 0; jq < 4; jq++) {
                #pragma unroll
                for (int jk = 0; jk < 4; jk++) {
                    acc[jq][jk] = fmaf(wv4.x, rcp_fast(fmaf(eq4[jq].x, ek4[jk].x, 1.0f)), acc[jq][jk]);
                    acc[jq][jk] = fmaf(wv4.y, rcp_fast(fmaf(eq4[jq].y, ek4[jk].y, 1.0f)), acc[jq][jk]);
                    acc[jq][jk] = fmaf(wv4.z, rcp_fast(fmaf(eq4[jq].z, ek4[jk].z, 1.0f)), acc[jq][jk]);
                    acc[jq][jk] = fmaf(wv4.w, rcp_fast(fmaf(eq4[jq].w, ek4[jk].w, 1.0f)), acc[jq][jk]);
                }
            }
        }
    }

    float* scb = sc + ((size_t)b * QS + q0) * KSZ + k0;
    #pragma unroll
    for (int jq = 0; jq < 4; jq++)
        #pragma unroll
        for (int jk = 0; jk < 4; jk++)
            scb[(size_t)(tq + 16 * jq) * KSZ + tk + 16 * jk] = acc[jq][jk];
}

// ---------------------------------------------------------------------------
// Kernel C: out[b][m][n] = sum_k exp(-2*sc[b,m,k]) * V[b,k,n] / rowsum(m).
// No max subtraction needed: |true score| <= 2*sum|w_v| ~ 18 -> exp fp32-safe;
// softmax shift cancels. Rowsum computed in-block during A staging (each block
// spans all of K). 64x64 tile, BK=32, double-buffered LDS, one barrier/step.
// A stored K-major (transposed) in LDS -> b128 fragment reads, stride 68.
// ---------------------------------------------------------------------------
__global__ __launch_bounds__(256) void pv_gemm_kernel(
    const float* __restrict__ sc, const float* __restrict__ val,
    float* __restrict__ outp)
{
    __shared__ float As[2][32][68];
    __shared__ float Bs[2][32][68];
    __shared__ float rsum[64];

    const int tid = threadIdx.x;
    const int b  = blockIdx.z;
    const int m0 = blockIdx.y * 64;
    const int n0 = blockIdx.x * 64;

    const float* scb = sc  + ((size_t)b * QS + m0) * KSZ;
    const float* vb  = val + (size_t)b * KSZ * DVV + n0;

    const int ar = tid >> 3;          // A rows ar, ar+32
    const int ak = (tid & 7) * 4;     // k offset within BK
    const int bk = tid >> 4;          // B k-rows bk, bk+16
    const int bn = (tid & 15) * 4;

    const float CN = -2.8853900817779268f;  // -2*log2(e): exp(-2x)=2^(x*CN)

    float4 ea0, ea1, vv0, vv1;
    float rs0 = 0.f, rs1 = 0.f;

    // prefetch tile 0
    {
        float4 r0 = *(const float4*)&scb[(size_t)ar * KSZ + ak];
        float4 r1 = *(const float4*)&scb[(size_t)(ar + 32) * KSZ + ak];
        ea0.x = exp2_fast(r0.x * CN); ea0.y = exp2_fast(r0.y * CN);
        ea0.z = exp2_fast(r0.z * CN); ea0.w = exp2_fast(r0.w * CN);
        ea1.x = exp2_fast(r1.x * CN); ea1.y = exp2_fast(r1.y * CN);
        ea1.z = exp2_fast(r1.z * CN); ea1.w = exp2_fast(r1.w * CN);
        vv0 = *(const float4*)&vb[(size_t)bk * DVV + bn];
        vv1 = *(const float4*)&vb[(size_t)(bk + 16) * DVV + bn];
    }
    // store tile 0 -> buf 0 (A transposed to k-major)
    As[0][ak + 0][ar] = ea0.x; As[0][ak + 1][ar] = ea0.y;
    As[0][ak + 2][ar] = ea0.z; As[0][ak + 3][ar] = ea0.w;
    As[0][ak + 0][ar + 32] = ea1.x; As[0][ak + 1][ar + 32] = ea1.y;
    As[0][ak + 2][ar + 32] = ea1.z; As[0][ak + 3][ar + 32] = ea1.w;
    *(float4*)&Bs[0][bk][bn]      = vv0;
    *(float4*)&Bs[0][bk + 16][bn] = vv1;
    rs0 += ea0.x + ea0.y + ea0.z + ea0.w;
    rs1 += ea1.x + ea1.y + ea1.z + ea1.w;

    const int tm = (tid & 15) * 4;
    const int tn = (tid >> 4) * 4;
    float acc[4][4] = {};

    for (int s = 0; s < 32; s++) {
        __syncthreads();
        const int buf = s & 1;
        if (s < 31) {
            const int k0 = (s + 1) * 32;
            float4 r0 = *(const float4*)&scb[(size_t)ar * KSZ + k0 + ak];
            float4 r1 = *(const float4*)&scb[(size_t)(ar + 32) * KSZ + k0 + ak];
            ea0.x = exp2_fast(r0.x * CN); ea0.y = exp2_fast(r0.y * CN);
            ea0.z = exp2_fast(r0.z * CN); ea0.w = exp2_fast(r0.w * CN);
            ea1.x = exp2_fast(r1.x * CN); ea1.y = exp2_fast(r1.y * CN);
            ea1.z = exp2_fast(r1.z * CN); ea1.w = exp2_fast(r1.w * CN);
            vv0 = *(const float4*)&vb[(size_t)(k0 + bk) * DVV + bn];
            vv1 = *(const float4*)&vb[(size_t)(k0 + bk + 16) * DVV + bn];
        }
        #pragma unroll
        for (int kk = 0; kk < 32; kk++) {
            float4 a4 = *(const float4*)&As[buf][kk][tm];
            float4 b4 = *(const float4*)&Bs[buf][kk][tn];
            acc[0][0] = fmaf(a4.x, b4.x, acc[0][0]); acc[0][1] = fmaf(a4.x, b4.y, acc[0][1]);
            acc[0][2] = fmaf(a4.x, b4.z, acc[0][2]); acc[0][3] = fmaf(a4.x, b4.w, acc[0][3]);
            acc[1][0] = fmaf(a4.y, b4.x, acc[1][0]); acc[1][1] = fmaf(a4.y, b4.y, acc[1][1]);
            acc[1][2] = fmaf(a4.y, b4.z, acc[1][2]); acc[1][3] = fmaf(a4.y, b4.w, acc[1][3]);
            acc[2][0] = fmaf(a4.z, b4.x, acc[2][0]); acc[2][1] = fmaf(a4.z, b4.y, acc[2][1]);
            acc[2][2] = fmaf(a4.z, b4.z, acc[2][2]); acc[2][3] = fmaf(a4.z, b4.w, acc[2][3]);
            acc[3][0] = fmaf(a4.w, b4.x, acc[3][0]); acc[3][1] = fmaf(a4.w, b4.y, acc[3][1]);
            acc[3][2] = fmaf(a4.w, b4.z, acc[3][2]); acc[3][3] = fmaf(a4.w, b4.w, acc[3][3]);
        }
        if (s < 31) {
            const int nb = buf ^ 1;
            As[nb][ak + 0][ar] = ea0.x; As[nb][ak + 1][ar] = ea0.y;
            As[nb][ak + 2][ar] = ea0.z; As[nb][ak + 3][ar] = ea0.w;
            As[nb][ak + 0][ar + 32] = ea1.x; As[nb][ak + 1][ar + 32] = ea1.y;
            As[nb][ak + 2][ar + 32] = ea1.z; As[nb][ak + 3][ar + 32] = ea1.w;
            *(float4*)&Bs[nb][bk][bn]      = vv0;
            *(float4*)&Bs[nb][bk + 16][bn] = vv1;
            rs0 += ea0.x + ea0.y + ea0.z + ea0.w;
            rs1 += ea1.x + ea1.y + ea1.z + ea1.w;
        }
    }

    // per-row sums: rows ar/ar+32 are loaded exclusively by the 8 aligned
    // lanes tid = ar*8..ar*8+7 -> 8-lane xor-shuffle reduce.
    #pragma unroll
    for (int m = 4; m; m >>= 1) {
        rs0 += __shfl_xor(rs0, m);
        rs1 += __shfl_xor(rs1, m);
    }
    if ((tid & 7) == 0) { rsum[ar] = rs0; rsum[ar + 32] = rs1; }
    __syncthreads();

    float* ob = outp + ((size_t)b * QS + m0) * DVV + n0;
    #pragma unroll
    for (int i = 0; i < 4; i++) {
        float inv = rcp_fast(rsum[tm + i]);
        float4 o;
        o.x = acc[i][0] * inv; o.y = acc[i][1] * inv;
        o.z = acc[i][2] * inv; o.w = acc[i][3] * inv;
        *(float4*)&ob[(size_t)(tm + i) * DVV + tn] = o;
    }
}

// ---------------------------------------------------------------------------
extern "C" void kernel_launch(void* const* d_in, const int* in_sizes, int n_in,
                              void* d_out, int out_size, void* d_ws, size_t ws_size,
                              hipStream_t stream)
{
    const float* queries = (const float*)d_in[0];
    const float* keys    = (const float*)d_in[1];
    const float* values  = (const float*)d_in[2];
    const float* Wq      = (const float*)d_in[3];
    const float* Wk      = (const float*)d_in[4];
    const float* wv      = (const float*)d_in[5];
    float* out = (float*)d_out;

    // workspace layout (floats): eq [B*Q*H] | ek [B*K*H] | scores [B*Q*K]
    float* eq = (float*)d_ws;
    float* ek = eq + (size_t)BB * QS * HH;
    float* sc = ek + (size_t)BB * KSZ * HH;

    const int nq_blocks = BB * QS / 16;   // 128
    const int nk_blocks = BB * KSZ / 16;  // 256
    proj_exp_kernel<<<dim3(nq_blocks + nk_blocks), 256, 0, stream>>>(
        queries, keys, Wq, Wk, eq, ek, nq_blocks);

    scores_kernel<<<dim3(KSZ / 64, QS / 64, BB), 256, 0, stream>>>(eq, ek, wv, sc);

    pv_gemm_kernel<<<dim3(DVV / 64, QS / 64, BB), 256, 0, stream>>>(sc, values, out);
}